// Round 9
// baseline (665.428 us; speedup 1.0000x reference)
//
#include <hip/hip_runtime.h>

#define G 128
#define P 512
#define K 16
#define NPTS (G * P)   // 65536

typedef _Float16 half8 __attribute__((ext_vector_type(8)));
typedef float    floatx4 __attribute__((ext_vector_type(4)));

__device__ __forceinline__ unsigned uminu(unsigned a, unsigned b) { return a < b ? a : b; }

// compare-exchange: a=min, b=max (folds to v_min_u32 + v_max_u32)
__device__ __forceinline__ void ce(unsigned& a, unsigned& b) {
    const unsigned lo = a < b ? a : b;
    const unsigned hi = a < b ? b : a;
    a = lo; b = hi;
}

// Batcher odd-even mergesort, n=16 (63 CEs, fully unrolled)
__device__ __forceinline__ void sort16(unsigned k[16]) {
#pragma unroll
    for (int p = 1; p < 16; p <<= 1) {
#pragma unroll
        for (int q = p; q >= 1; q >>= 1) {
#pragma unroll
            for (int j = q % p; j + q < 16; j += 2 * q) {
#pragma unroll
                for (int i = 0; i < q; ++i) {
                    const int a = i + j, b2 = i + j + q;
                    if (b2 < 16 && (a / (2 * p)) == (b2 / (2 * p)))
                        ce(k[a], k[b2]);
                }
            }
        }
    }
}

// best (sorted asc) := sorted 16 smallest of best ∪ kb (kb sorted asc).
__device__ __forceinline__ void halfmerge(unsigned best[16], const unsigned kb[16]) {
#pragma unroll
    for (int i = 0; i < 16; ++i) best[i] = uminu(best[i], kb[15 - i]);
#pragma unroll
    for (int d = 8; d >= 1; d >>= 1)
#pragma unroll
        for (int i = 0; i < 16; ++i)
            if ((i & d) == 0) ce(best[i], best[i + d]);
}

// ---------------------------------------------------------------------------
// prep element: [wl;wr] fp32 -> fp16 MFMA B-fragment layout.
// frag (ntile,kt): lane l holds B[kt*32+(l>>4)*8+j][ntile*16+(l&15)], j=0..7.
// ---------------------------------------------------------------------------
template <int KT, int NIN, int NOUT>
__device__ __forceinline__ void prep_elem(int e, const float* __restrict__ wl,
                                          const float* __restrict__ wr,
                                          _Float16* __restrict__ wf) {
    const int fr   = e >> 9;
    const int lane = (e >> 3) & 63;
    const int j    = e & 7;
    const int ntile = fr / KT;
    const int kt    = fr - ntile * KT;
    const int k = kt * 32 + ((lane >> 4) << 3) + j;
    const int n = ntile * 16 + (lane & 15);
    const float v = (k < NIN) ? wl[k * NOUT + n] : wr[(k - NIN) * NOUT + n];
    wf[e] = (_Float16)v;
}

// ---------------------------------------------------------------------------
// Fused pre-pass: blocks [0,1024) = KNN, [1024,3072) = x fp32->fp16 cvt,
// [3072,3152) = weight prep. (unchanged from round 8)
// ---------------------------------------------------------------------------
__global__ __launch_bounds__(512, 4)
void pre_kernel(const int* __restrict__ coo, int* __restrict__ idx_out,
                const float* __restrict__ x, _Float16* __restrict__ x16,
                const float* __restrict__ wl0, const float* __restrict__ wr0,
                const float* __restrict__ wl1, const float* __restrict__ wr1,
                const float* __restrict__ wl2, const float* __restrict__ wr2,
                _Float16* __restrict__ wf0, _Float16* __restrict__ wf1,
                _Float16* __restrict__ wf2) {
    __shared__ float2 sxy[P];
    __shared__ unsigned mk[7][64][17];
    const int b   = blockIdx.x;
    const int tid = threadIdx.x;

    if (b < 1024) {
        // ---------------- KNN ----------------
        const int g   = b >> 3;
        const int t0  = (b & 7) * 64;
        const int tgt = tid & 63;
        const int sub = tid >> 6;          // 0..7, wave-uniform

        for (int i = tid; i < P; i += 512) {
            const int* cp = coo + (size_t)(g * P + i) * 3;
            sxy[i] = make_float2((float)cp[0], (float)cp[1]);
        }
        __syncthreads();

        const int tg = t0 + tgt;
        const float px = sxy[tg].x, py = sxy[tg].y;

        unsigned best[K];
#pragma unroll
        for (int k = 0; k < K; ++k) best[k] = 0xFFFFFFF0u + k;  // sorted tail

        const int s0 = sub * 64;
#pragma unroll
        for (int batch = 0; batch < 4; ++batch) {
            unsigned kb[K];
#pragma unroll
            for (int j = 0; j < 16; ++j) {
                const int s = s0 + batch * 16 + j;
                const float2 c = sxy[s];              // uniform -> broadcast
                const float dx = px - c.x, dy = py - c.y;
                const float keyf = fmaf(fmaf(dx, dx, dy * dy), 512.f, (float)s);
                unsigned key = (unsigned)keyf;        // exact (< 2^20)
                if (s == tg) key = 0xFFFFFFFFu;       // loop=False
                kb[j] = key;
            }
            sort16(kb);
            halfmerge(best, kb);
        }

        // single-barrier merge: subs 1-7 publish, sub 0 folds all 7
        if (sub != 0) {
#pragma unroll
            for (int k = 0; k < K; ++k) mk[sub - 1][tgt][k] = best[k];
        }
        __syncthreads();
        if (sub == 0) {
#pragma unroll 1
            for (int ss = 0; ss < 7; ++ss) {
                unsigned pb[K];
#pragma unroll
                for (int k = 0; k < K; ++k) pb[k] = mk[ss][tgt][k];
                halfmerge(best, pb);
            }
            int4* op = (int4*)(idx_out + (size_t)(g * P + tg) * K);
#pragma unroll
            for (int q4 = 0; q4 < 4; ++q4) {
                int4 o;
                o.x = (int)(best[q4 * 4 + 0] & (unsigned)(P - 1));
                o.y = (int)(best[q4 * 4 + 1] & (unsigned)(P - 1));
                o.z = (int)(best[q4 * 4 + 2] & (unsigned)(P - 1));
                o.w = (int)(best[q4 * 4 + 3] & (unsigned)(P - 1));
                op[q4] = o;
            }
        }
    } else if (b < 3072) {
        // ---------------- cvt: x fp32 -> fp16, 8 elems/thread ----------------
        const int i = (b - 1024) * 512 + tid;      // < 1,048,576 exactly
        const float4* p = (const float4*)(x + (size_t)i * 8);
        const float4 a = p[0], bq = p[1];
        half8 o;
        o[0] = (_Float16)a.x;  o[1] = (_Float16)a.y;
        o[2] = (_Float16)a.z;  o[3] = (_Float16)a.w;
        o[4] = (_Float16)bq.x; o[5] = (_Float16)bq.y;
        o[6] = (_Float16)bq.z; o[7] = (_Float16)bq.w;
        *(half8*)(x16 + (size_t)i * 8) = o;
    } else {
        // ---------------- prep ----------------
        const int e = (b - 3072) * 512 + tid;      // < 40,960 exactly
        if (e < 24576)      prep_elem<8, 128, 96>(e,         wl0, wr0, wf0);
        else if (e < 36864) prep_elem<6,  96, 64>(e - 24576, wl1, wr1, wf1);
        else                prep_elem<4,  64, 32>(e - 36864, wl2, wr2, wf2);
    }
}

// ---------------------------------------------------------------------------
// Software grid barrier. Safe because all 1024 blocks are co-resident:
// 4 blocks/CU x 256 CUs, resources (VGPR<=128, LDS ~18KB) leave slack.
// Counter in d_ws, zeroed by hipMemsetAsync before launch.
// ---------------------------------------------------------------------------
__device__ __forceinline__ void gridbar(unsigned* ctr) {
    __syncthreads();
    if (threadIdx.x == 0) {
        __hip_atomic_fetch_add(ctr, 1u, __ATOMIC_ACQ_REL, __HIP_MEMORY_SCOPE_AGENT);
        unsigned v;
        do {
            __builtin_amdgcn_s_sleep(2);
            v = __hip_atomic_load(ctr, __ATOMIC_ACQUIRE, __HIP_MEMORY_SCOPE_AGENT);
        } while (v < 1024u);
    }
    __syncthreads();
}

// ---------------------------------------------------------------------------
// SAGE layer body (as in round-8 sage_kernel): 256 thr / 4 waves, 64 points,
// XCD-swizzled block decode, mean-half in LDS (stride 136), root-half A-frags
// straight from global. POOL=true (last layer): skip h3 store; per-block
// channel-max -> pool_part[g*8+chunk][32].
// ---------------------------------------------------------------------------
template <int CIN, int NOUT, bool POOL>
__device__ __forceinline__ void sage_body(
    const int b, const int tid, _Float16* __restrict__ As, float (*ps)[16],
    const _Float16* __restrict__ hin, const int* __restrict__ idxg,
    const _Float16* __restrict__ wf, const float* __restrict__ bias,
    _Float16* __restrict__ hout, float* __restrict__ pool_part) {
    constexpr int KTm = CIN / 32;     // mean-half MFMA k-steps
    constexpr int KT  = CIN / 16;     // total k-steps (mean + root)
    constexpr int NH  = NOUT / 32;    // N-tiles per wave
    constexpr int RS  = 136;          // LDS row stride in halves

    const int slot = b >> 3;
    const int g    = (b & 7) | ((slot & 15) << 3);
    const int chunk = slot >> 4;
    const int n0   = g * P + chunk * 64;
    const _Float16* __restrict__ hg = hin + (size_t)(g * P) * CIN;

    const int pt = tid >> 2;
    const int q  = tid & 3;

    // 16 neighbor indices -> registers (idx rows L2-hot)
    const int4* ip = (const int4*)(idxg + (size_t)(n0 + pt) * K);
    const int4 na = ip[0], nb4 = ip[1], nc = ip[2], nd = ip[3];
    const int nn[16] = {na.x, na.y, na.z, na.w, nb4.x, nb4.y, nb4.z, nb4.w,
                        nc.x, nc.y, nc.z, nc.w, nd.x, nd.y, nd.z, nd.w};

#pragma unroll 1
    for (int c = 0; c < KTm; ++c) {
        const int ch = c * 32 + q * 8;
        half8 a0 = {}; half8 a1 = {};
#pragma unroll
        for (int k = 0; k < 16; k += 4) {
            const half8 v0 = *(const half8*)(hg + (size_t)nn[k + 0] * CIN + ch);
            const half8 v1 = *(const half8*)(hg + (size_t)nn[k + 1] * CIN + ch);
            const half8 v2 = *(const half8*)(hg + (size_t)nn[k + 2] * CIN + ch);
            const half8 v3 = *(const half8*)(hg + (size_t)nn[k + 3] * CIN + ch);
            a0 += v0; a1 += v1; a0 += v2; a1 += v3;
        }
        half8 m;
#pragma unroll
        for (int e = 0; e < 8; ++e)
            m[e] = (_Float16)(((float)a0[e] + (float)a1[e]) * 0.0625f);
        *(half8*)&As[pt * RS + (c * 4 + q) * 8] = m;
    }

    const int l  = tid & 63;
    const int wv = tid >> 6;
    const int mh = wv & 1;
    const int nh = wv >> 1;
    const int lm = l & 15, lq = l >> 4;

    float bs[NH];
#pragma unroll
    for (int nt = 0; nt < NH; ++nt)
        bs[nt] = bias[nh * (NOUT / 2) + nt * 16 + lm];

    __syncthreads();

    floatx4 acc[2][NH];
#pragma unroll
    for (int mt = 0; mt < 2; ++mt)
#pragma unroll
        for (int nt = 0; nt < NH; ++nt) {
            floatx4 z = {0.f, 0.f, 0.f, 0.f};
            acc[mt][nt] = z;
        }

#pragma unroll
    for (int kt = 0; kt < KT; ++kt) {
        half8 bfr[NH];
#pragma unroll
        for (int nt = 0; nt < NH; ++nt) {
            const int ng = nh * NH + nt;
            bfr[nt] = *(const half8*)(wf + ((size_t)(ng * KT + kt) * 64 + l) * 8);
        }
#pragma unroll
        for (int mt = 0; mt < 2; ++mt) {
            const int row = mh * 32 + mt * 16 + lm;
            half8 a;
            if (kt < KTm) {
                a = *(const half8*)&As[row * RS + (kt * 4 + lq) * 8];
            } else {
                a = *(const half8*)(hin + (size_t)(n0 + row) * CIN +
                                    (kt - KTm) * 32 + lq * 8);
            }
#pragma unroll
            for (int nt = 0; nt < NH; ++nt)
                acc[mt][nt] = __builtin_amdgcn_mfma_f32_16x16x32_f16(
                    a, bfr[nt], acc[mt][nt], 0, 0, 0);
        }
    }

    if constexpr (POOL) {
        // channel n = nh*16 + lm; per-lane max over 2 mt x 4 r values
        float vmax = -3.4e38f;
#pragma unroll
        for (int mt = 0; mt < 2; ++mt)
#pragma unroll
            for (int r = 0; r < 4; ++r) {
                float v = acc[mt][0][r] + bs[0];
                v = v > 0.f ? v : 0.f;
                vmax = fmaxf(vmax, v);
            }
        // reduce over lq (lanes 16 apart hold same channel)
        vmax = fmaxf(vmax, __shfl_xor(vmax, 16, 64));
        vmax = fmaxf(vmax, __shfl_xor(vmax, 32, 64));
        if (lq == 0) ps[wv][lm] = vmax;
        __syncthreads();
        if (tid < 32) {
            const int nh2 = tid >> 4, lm2 = tid & 15;
            const float m = fmaxf(ps[nh2 * 2][lm2], ps[nh2 * 2 + 1][lm2]);
            pool_part[(size_t)(g * 8 + chunk) * 32 + tid] = m;
        }
    } else {
#pragma unroll
        for (int mt = 0; mt < 2; ++mt)
#pragma unroll
            for (int nt = 0; nt < NH; ++nt) {
                const int n = nh * (NOUT / 2) + nt * 16 + lm;
#pragma unroll
                for (int r = 0; r < 4; ++r) {
                    const int p = n0 + mh * 32 + mt * 16 + lq * 4 + r;
                    float v = acc[mt][nt][r] + bs[nt];
                    v = v > 0.f ? v : 0.f;
                    hout[(size_t)p * NOUT + n] = (_Float16)v;
                }
            }
    }
}

// ---------------------------------------------------------------------------
// Fused GNN: sage L0 -> bar -> L1 -> bar -> L2(+pool) -> bar -> head.
// 1024 blocks x 256 thr, all co-resident (see gridbar comment).
// ---------------------------------------------------------------------------
__global__ __launch_bounds__(256, 4)
void gnn_kernel(const _Float16* __restrict__ x16, const int* __restrict__ idx,
                const _Float16* __restrict__ wf0, const float* __restrict__ b0,
                const _Float16* __restrict__ wf1, const float* __restrict__ b1,
                const _Float16* __restrict__ wf2, const float* __restrict__ b2,
                _Float16* __restrict__ h1, _Float16* __restrict__ h2,
                float* __restrict__ pool_part,
                const float* __restrict__ lw0, const float* __restrict__ lb0,
                const float* __restrict__ lw1, const float* __restrict__ lb1,
                float* __restrict__ out, unsigned* __restrict__ ctr) {
    __shared__ _Float16 As[64 * 136];   // 17 KB, reused across phases
    __shared__ float ps[4][16];
    __shared__ float pooled[32];
    __shared__ float hid[32];

    const int b   = blockIdx.x;
    const int tid = threadIdx.x;

    sage_body<128, 96, false>(b, tid, As, ps, x16, idx, wf0, b0, h1, nullptr);
    gridbar(ctr + 0);
    sage_body< 96, 64, false>(b, tid, As, ps, h1, idx, wf1, b1, h2, nullptr);
    gridbar(ctr + 16);
    sage_body< 64, 32, true >(b, tid, As, ps, h2, idx, wf2, b2, nullptr, pool_part);
    gridbar(ctr + 32);

    if (b < 128) {
        // head for graph g = b (XCD b%8 matches producer XCD)
        const int g = b;
        if (tid < 32) {
            float m = pool_part[(size_t)(g * 8) * 32 + tid];
#pragma unroll
            for (int c = 1; c < 8; ++c)
                m = fmaxf(m, pool_part[(size_t)(g * 8 + c) * 32 + tid]);
            pooled[tid] = m;
        }
        __syncthreads();
        if (tid < 32) {
            float a = lb0[tid];
#pragma unroll
            for (int i = 0; i < 32; ++i) a += pooled[i] * lw0[i * 32 + tid];
            hid[tid] = a > 0.f ? a : 0.f;
        }
        __syncthreads();
        if (tid < 3) {
            float a = lb1[tid];
#pragma unroll
            for (int i = 0; i < 32; ++i) a += hid[i] * lw1[i * 3 + tid];
            out[g * 3 + tid] = a;
        }
    }
}

// ---------------------------------------------------------------------------
extern "C" void kernel_launch(void* const* d_in, const int* in_sizes, int n_in,
                              void* d_out, int out_size, void* d_ws, size_t ws_size,
                              hipStream_t stream) {
    const float* x   = (const float*)d_in[0];
    const int*   coo = (const int*)  d_in[1];
    const float* wl0 = (const float*)d_in[2];
    const float* wr0 = (const float*)d_in[3];
    const float* b0  = (const float*)d_in[4];
    const float* wl1 = (const float*)d_in[5];
    const float* wr1 = (const float*)d_in[6];
    const float* b1  = (const float*)d_in[7];
    const float* wl2 = (const float*)d_in[8];
    const float* wr2 = (const float*)d_in[9];
    const float* b2  = (const float*)d_in[10];
    const float* lw0 = (const float*)d_in[11];
    const float* lb0 = (const float*)d_in[12];
    const float* lw1 = (const float*)d_in[13];
    const float* lb1 = (const float*)d_in[14];
    float* out = (float*)d_out;

    char* ws = (char*)d_ws;
    // Workspace (bytes):
    //   wf0 : 49,152      @ 0
    //   wf1 : 24,576      @ 49,152
    //   wf2 :  8,192      @ 73,728
    //   idx :  4,194,304  @ 81,920
    //   x16 : 16,777,216  @ 4,276,224   (65536 x 128 fp16)
    //   h1  : 12,582,912  @ 21,053,440  (fp16)
    //   h2  :  8,388,608  @ 33,636,352  (fp16)
    //   pool:    131,072  @ 42,024,960  (1024 x 32 fp32)
    //   ctr :        192  @ 42,156,032  (3 x 64B-spaced counters)
    _Float16* wf0 = (_Float16*)(ws + 0);
    _Float16* wf1 = (_Float16*)(ws + 49152);
    _Float16* wf2 = (_Float16*)(ws + 73728);
    int*      idx = (int*)     (ws + 81920);
    _Float16* x16 = (_Float16*)(ws + 4276224);
    _Float16* h1  = (_Float16*)(ws + 21053440);
    _Float16* h2  = (_Float16*)(ws + 33636352);
    float*    pool= (float*)   (ws + 42024960);
    unsigned* ctr = (unsigned*)(ws + 42156032);

    hipMemsetAsync(ctr, 0, 192, stream);   // zero grid-barrier counters

    pre_kernel<<<3152, 512, 0, stream>>>(coo, idx, x, x16,
                                         wl0, wr0, wl1, wr1, wl2, wr2,
                                         wf0, wf1, wf2);

    gnn_kernel<<<1024, 256, 0, stream>>>(x16, idx, wf0, b0, wf1, b1, wf2, b2,
                                         h1, h2, pool, lw0, lb0, lw1, lb1,
                                         out, ctr);
}

// Round 10
// 238.094 us; speedup vs baseline: 2.7948x; 2.7948x over previous
//
#include <hip/hip_runtime.h>

#define G 128
#define P 512
#define K 16
#define NPTS (G * P)   // 65536

typedef _Float16 half8 __attribute__((ext_vector_type(8)));
typedef float    floatx4 __attribute__((ext_vector_type(4)));

__device__ __forceinline__ unsigned uminu(unsigned a, unsigned b) { return a < b ? a : b; }

// compare-exchange: a=min, b=max (folds to v_min_u32 + v_max_u32)
__device__ __forceinline__ void ce(unsigned& a, unsigned& b) {
    const unsigned lo = a < b ? a : b;
    const unsigned hi = a < b ? b : a;
    a = lo; b = hi;
}

// Batcher odd-even mergesort, n=16 (63 CEs, fully unrolled)
__device__ __forceinline__ void sort16(unsigned k[16]) {
#pragma unroll
    for (int p = 1; p < 16; p <<= 1) {
#pragma unroll
        for (int q = p; q >= 1; q >>= 1) {
#pragma unroll
            for (int j = q % p; j + q < 16; j += 2 * q) {
#pragma unroll
                for (int i = 0; i < q; ++i) {
                    const int a = i + j, b2 = i + j + q;
                    if (b2 < 16 && (a / (2 * p)) == (b2 / (2 * p)))
                        ce(k[a], k[b2]);
                }
            }
        }
    }
}

// best (sorted asc) := sorted 16 smallest of best ∪ kb (kb sorted asc).
__device__ __forceinline__ void halfmerge(unsigned best[16], const unsigned kb[16]) {
#pragma unroll
    for (int i = 0; i < 16; ++i) best[i] = uminu(best[i], kb[15 - i]);
#pragma unroll
    for (int d = 8; d >= 1; d >>= 1)
#pragma unroll
        for (int i = 0; i < 16; ++i)
            if ((i & d) == 0) ce(best[i], best[i + d]);
}

// ---------------------------------------------------------------------------
// prep element: [wl;wr] fp32 -> fp16 MFMA B-fragment layout.
// frag (ntile,kt): lane l holds B[kt*32+(l>>4)*8+j][ntile*16+(l&15)], j=0..7.
// ---------------------------------------------------------------------------
template <int KT, int NIN, int NOUT>
__device__ __forceinline__ void prep_elem(int e, const float* __restrict__ wl,
                                          const float* __restrict__ wr,
                                          _Float16* __restrict__ wf) {
    const int fr   = e >> 9;
    const int lane = (e >> 3) & 63;
    const int j    = e & 7;
    const int ntile = fr / KT;
    const int kt    = fr - ntile * KT;
    const int k = kt * 32 + ((lane >> 4) << 3) + j;
    const int n = ntile * 16 + (lane & 15);
    const float v = (k < NIN) ? wl[k * NOUT + n] : wr[(k - NIN) * NOUT + n];
    wf[e] = (_Float16)v;
}

// ---------------------------------------------------------------------------
// Fused pre-pass: blocks [0,1024) = KNN, [1024,3072) = x fp32->fp16 cvt,
// [3072,3152) = weight prep. (proven in round 8)
// ---------------------------------------------------------------------------
__global__ __launch_bounds__(512, 4)
void pre_kernel(const int* __restrict__ coo, int* __restrict__ idx_out,
                const float* __restrict__ x, _Float16* __restrict__ x16,
                const float* __restrict__ wl0, const float* __restrict__ wr0,
                const float* __restrict__ wl1, const float* __restrict__ wr1,
                const float* __restrict__ wl2, const float* __restrict__ wr2,
                _Float16* __restrict__ wf0, _Float16* __restrict__ wf1,
                _Float16* __restrict__ wf2) {
    __shared__ float2 sxy[P];
    __shared__ unsigned mk[7][64][17];
    const int b   = blockIdx.x;
    const int tid = threadIdx.x;

    if (b < 1024) {
        // ---------------- KNN ----------------
        const int g   = b >> 3;
        const int t0  = (b & 7) * 64;
        const int tgt = tid & 63;
        const int sub = tid >> 6;          // 0..7, wave-uniform

        for (int i = tid; i < P; i += 512) {
            const int* cp = coo + (size_t)(g * P + i) * 3;
            sxy[i] = make_float2((float)cp[0], (float)cp[1]);
        }
        __syncthreads();

        const int tg = t0 + tgt;
        const float px = sxy[tg].x, py = sxy[tg].y;

        unsigned best[K];
#pragma unroll
        for (int k = 0; k < K; ++k) best[k] = 0xFFFFFFF0u + k;  // sorted tail

        const int s0 = sub * 64;
#pragma unroll
        for (int batch = 0; batch < 4; ++batch) {
            unsigned kb[K];
#pragma unroll
            for (int j = 0; j < 16; ++j) {
                const int s = s0 + batch * 16 + j;
                const float2 c = sxy[s];              // uniform -> broadcast
                const float dx = px - c.x, dy = py - c.y;
                const float keyf = fmaf(fmaf(dx, dx, dy * dy), 512.f, (float)s);
                unsigned key = (unsigned)keyf;        // exact (< 2^20)
                if (s == tg) key = 0xFFFFFFFFu;       // loop=False
                kb[j] = key;
            }
            sort16(kb);
            halfmerge(best, kb);
        }

        // single-barrier merge: subs 1-7 publish, sub 0 folds all 7
        if (sub != 0) {
#pragma unroll
            for (int k = 0; k < K; ++k) mk[sub - 1][tgt][k] = best[k];
        }
        __syncthreads();
        if (sub == 0) {
#pragma unroll 1
            for (int ss = 0; ss < 7; ++ss) {
                unsigned pb[K];
#pragma unroll
                for (int k = 0; k < K; ++k) pb[k] = mk[ss][tgt][k];
                halfmerge(best, pb);
            }
            int4* op = (int4*)(idx_out + (size_t)(g * P + tg) * K);
#pragma unroll
            for (int q4 = 0; q4 < 4; ++q4) {
                int4 o;
                o.x = (int)(best[q4 * 4 + 0] & (unsigned)(P - 1));
                o.y = (int)(best[q4 * 4 + 1] & (unsigned)(P - 1));
                o.z = (int)(best[q4 * 4 + 2] & (unsigned)(P - 1));
                o.w = (int)(best[q4 * 4 + 3] & (unsigned)(P - 1));
                op[q4] = o;
            }
        }
    } else if (b < 3072) {
        // ---------------- cvt: x fp32 -> fp16, 8 elems/thread ----------------
        const int i = (b - 1024) * 512 + tid;      // < 1,048,576 exactly
        const float4* p = (const float4*)(x + (size_t)i * 8);
        const float4 a = p[0], bq = p[1];
        half8 o;
        o[0] = (_Float16)a.x;  o[1] = (_Float16)a.y;
        o[2] = (_Float16)a.z;  o[3] = (_Float16)a.w;
        o[4] = (_Float16)bq.x; o[5] = (_Float16)bq.y;
        o[6] = (_Float16)bq.z; o[7] = (_Float16)bq.w;
        *(half8*)(x16 + (size_t)i * 8) = o;
    } else {
        // ---------------- prep ----------------
        const int e = (b - 3072) * 512 + tid;      // < 40,960 exactly
        if (e < 24576)      prep_elem<8, 128, 96>(e,         wl0, wr0, wf0);
        else if (e < 36864) prep_elem<6,  96, 64>(e - 24576, wl1, wr1, wf1);
        else                prep_elem<4,  64, 32>(e - 36864, wl2, wr2, wf2);
    }
}

// ---------------------------------------------------------------------------
// Fused SAGE: out = relu([mean_nbr(h) | h] @ [wl;wr] + b), f16 MFMA.
// Block: 256 thr / 4 waves, 64 points, XCD-swizzled (graph g -> XCD g%8).
// POOL=true (last layer): no h3 store; per-block channel-max -> pool_part,
// then per-graph "last block" (atomicAdd on gctr[g], prev==7, zero spin)
// runs the MLP head for its graph. All 8 blocks of a graph share one XCD.
// ---------------------------------------------------------------------------
template <int CIN, int NOUT, bool POOL>
__global__ __launch_bounds__(256, 4)
void sage_kernel(const _Float16* __restrict__ hin, const int* __restrict__ idxg,
                 const _Float16* __restrict__ wf, const float* __restrict__ bias,
                 _Float16* __restrict__ hout,
                 float* __restrict__ pool_part, unsigned* __restrict__ gctr,
                 const float* __restrict__ lw0, const float* __restrict__ lb0,
                 const float* __restrict__ lw1, const float* __restrict__ lb1,
                 float* __restrict__ out) {
    constexpr int KTm = CIN / 32;     // mean-half MFMA k-steps
    constexpr int KT  = CIN / 16;     // total k-steps (mean + root)
    constexpr int NH  = NOUT / 32;    // N-tiles per wave
    constexpr int RS  = 136;          // LDS row stride in halves

    __shared__ _Float16 As[64 * RS];  // 17 KB

    const int tid  = threadIdx.x;
    const int b    = blockIdx.x;       // 0..1023
    const int slot = b >> 3;
    const int g    = (b & 7) | ((slot & 15) << 3);
    const int chunk = slot >> 4;
    const int n0   = g * P + chunk * 64;
    const _Float16* __restrict__ hg = hin + (size_t)(g * P) * CIN;

    const int pt = tid >> 2;
    const int q  = tid & 3;

    // 16 neighbor indices -> registers
    const int4* ip = (const int4*)(idxg + (size_t)(n0 + pt) * K);
    const int4 na = ip[0], nb4 = ip[1], nc = ip[2], nd = ip[3];
    const int nn[16] = {na.x, na.y, na.z, na.w, nb4.x, nb4.y, nb4.z, nb4.w,
                        nc.x, nc.y, nc.z, nc.w, nd.x, nd.y, nd.z, nd.w};

#pragma unroll 1
    for (int c = 0; c < KTm; ++c) {
        const int ch = c * 32 + q * 8;
        half8 a0 = {}; half8 a1 = {};
#pragma unroll
        for (int k = 0; k < 16; k += 4) {
            const half8 v0 = *(const half8*)(hg + (size_t)nn[k + 0] * CIN + ch);
            const half8 v1 = *(const half8*)(hg + (size_t)nn[k + 1] * CIN + ch);
            const half8 v2 = *(const half8*)(hg + (size_t)nn[k + 2] * CIN + ch);
            const half8 v3 = *(const half8*)(hg + (size_t)nn[k + 3] * CIN + ch);
            a0 += v0; a1 += v1; a0 += v2; a1 += v3;
        }
        half8 m;
#pragma unroll
        for (int e = 0; e < 8; ++e)
            m[e] = (_Float16)(((float)a0[e] + (float)a1[e]) * 0.0625f);
        *(half8*)&As[pt * RS + (c * 4 + q) * 8] = m;
    }

    const int l  = tid & 63;
    const int wv = tid >> 6;
    const int mh = wv & 1;
    const int nh = wv >> 1;
    const int lm = l & 15, lq = l >> 4;

    float bs[NH];
#pragma unroll
    for (int nt = 0; nt < NH; ++nt)
        bs[nt] = bias[nh * (NOUT / 2) + nt * 16 + lm];

    __syncthreads();

    floatx4 acc[2][NH];
#pragma unroll
    for (int mt = 0; mt < 2; ++mt)
#pragma unroll
        for (int nt = 0; nt < NH; ++nt) {
            floatx4 z = {0.f, 0.f, 0.f, 0.f};
            acc[mt][nt] = z;
        }

#pragma unroll
    for (int kt = 0; kt < KT; ++kt) {
        half8 bfr[NH];
#pragma unroll
        for (int nt = 0; nt < NH; ++nt) {
            const int ng = nh * NH + nt;
            bfr[nt] = *(const half8*)(wf + ((size_t)(ng * KT + kt) * 64 + l) * 8);
        }
#pragma unroll
        for (int mt = 0; mt < 2; ++mt) {
            const int row = mh * 32 + mt * 16 + lm;
            half8 a;
            if (kt < KTm) {
                a = *(const half8*)&As[row * RS + (kt * 4 + lq) * 8];
            } else {
                a = *(const half8*)(hin + (size_t)(n0 + row) * CIN +
                                    (kt - KTm) * 32 + lq * 8);
            }
#pragma unroll
            for (int nt = 0; nt < NH; ++nt)
                acc[mt][nt] = __builtin_amdgcn_mfma_f32_16x16x32_f16(
                    a, bfr[nt], acc[mt][nt], 0, 0, 0);
        }
    }

    if constexpr (!POOL) {
#pragma unroll
        for (int mt = 0; mt < 2; ++mt)
#pragma unroll
            for (int nt = 0; nt < NH; ++nt) {
                const int n = nh * (NOUT / 2) + nt * 16 + lm;
#pragma unroll
                for (int r = 0; r < 4; ++r) {
                    const int p = n0 + mh * 32 + mt * 16 + lq * 4 + r;
                    float v = acc[mt][nt][r] + bs[nt];
                    v = v > 0.f ? v : 0.f;
                    hout[(size_t)p * NOUT + n] = (_Float16)v;
                }
            }
    } else {
        // ---- per-block channel max (relu'd) -> pool_part[g*8+chunk][32] ----
        __shared__ float ps[4][16];
        __shared__ float pooled[32];
        __shared__ float hid[32];
        __shared__ int islast;

        float vmax = -3.4e38f;
#pragma unroll
        for (int mt = 0; mt < 2; ++mt)
#pragma unroll
            for (int r = 0; r < 4; ++r) {
                float v = acc[mt][0][r] + bs[0];
                v = v > 0.f ? v : 0.f;
                vmax = fmaxf(vmax, v);
            }
        vmax = fmaxf(vmax, __shfl_xor(vmax, 16, 64));
        vmax = fmaxf(vmax, __shfl_xor(vmax, 32, 64));
        if (lq == 0) ps[wv][lm] = vmax;
        __syncthreads();
        if (tid < 32) {
            const int nh2 = tid >> 4, lm2 = tid & 15;
            const float m = fmaxf(ps[nh2 * 2][lm2], ps[nh2 * 2 + 1][lm2]);
            pool_part[(size_t)(g * 8 + chunk) * 32 + tid] = m;
        }
        __threadfence();        // make pool_part visible device-wide
        __syncthreads();        // order tid0's atomic after all fences
        if (tid == 0) {
            const unsigned prev = __hip_atomic_fetch_add(
                &gctr[g], 1u, __ATOMIC_ACQ_REL, __HIP_MEMORY_SCOPE_AGENT);
            islast = (prev == 7u);
        }
        __syncthreads();
        if (islast) {
            // ---- head for graph g (acquire above invalidated L1) ----
            if (tid < 32) {
                float m = pool_part[(size_t)(g * 8) * 32 + tid];
#pragma unroll
                for (int c = 1; c < 8; ++c)
                    m = fmaxf(m, pool_part[(size_t)(g * 8 + c) * 32 + tid]);
                pooled[tid] = m;
            }
            __syncthreads();
            if (tid < 32) {
                float a = lb0[tid];
#pragma unroll
                for (int i = 0; i < 32; ++i) a += pooled[i] * lw0[i * 32 + tid];
                hid[tid] = a > 0.f ? a : 0.f;
            }
            __syncthreads();
            if (tid < 3) {
                float a = lb1[tid];
#pragma unroll
                for (int i = 0; i < 32; ++i) a += hid[i] * lw1[i * 3 + tid];
                out[g * 3 + tid] = a;
            }
        }
    }
}

// ---------------------------------------------------------------------------
extern "C" void kernel_launch(void* const* d_in, const int* in_sizes, int n_in,
                              void* d_out, int out_size, void* d_ws, size_t ws_size,
                              hipStream_t stream) {
    const float* x   = (const float*)d_in[0];
    const int*   coo = (const int*)  d_in[1];
    const float* wl0 = (const float*)d_in[2];
    const float* wr0 = (const float*)d_in[3];
    const float* b0  = (const float*)d_in[4];
    const float* wl1 = (const float*)d_in[5];
    const float* wr1 = (const float*)d_in[6];
    const float* b1  = (const float*)d_in[7];
    const float* wl2 = (const float*)d_in[8];
    const float* wr2 = (const float*)d_in[9];
    const float* b2  = (const float*)d_in[10];
    const float* lw0 = (const float*)d_in[11];
    const float* lb0 = (const float*)d_in[12];
    const float* lw1 = (const float*)d_in[13];
    const float* lb1 = (const float*)d_in[14];
    float* out = (float*)d_out;

    char* ws = (char*)d_ws;
    // Workspace (bytes):
    //   wf0 : 49,152      @ 0
    //   wf1 : 24,576      @ 49,152
    //   wf2 :  8,192      @ 73,728
    //   idx :  4,194,304  @ 81,920
    //   x16 : 16,777,216  @ 4,276,224   (65536 x 128 fp16)
    //   h1  : 12,582,912  @ 21,053,440  (fp16)
    //   h2  :  8,388,608  @ 33,636,352  (fp16)
    //   pool:    131,072  @ 42,024,960  (1024 x 32 fp32)
    //   gctr:        512  @ 42,156,032  (128 u32)
    _Float16* wf0 = (_Float16*)(ws + 0);
    _Float16* wf1 = (_Float16*)(ws + 49152);
    _Float16* wf2 = (_Float16*)(ws + 73728);
    int*      idx = (int*)     (ws + 81920);
    _Float16* x16 = (_Float16*)(ws + 4276224);
    _Float16* h1  = (_Float16*)(ws + 21053440);
    _Float16* h2  = (_Float16*)(ws + 33636352);
    float*    pool= (float*)   (ws + 42024960);
    unsigned* gctr= (unsigned*)(ws + 42156032);

    hipMemsetAsync(gctr, 0, 512, stream);   // zero per-graph head counters

    pre_kernel<<<3152, 512, 0, stream>>>(coo, idx, x, x16,
                                         wl0, wr0, wl1, wr1, wl2, wr2,
                                         wf0, wf1, wf2);

    sage_kernel<128, 96, false><<<1024, 256, 0, stream>>>(
        x16, idx, wf0, b0, h1, nullptr, nullptr,
        nullptr, nullptr, nullptr, nullptr, nullptr);
    sage_kernel< 96, 64, false><<<1024, 256, 0, stream>>>(
        h1, idx, wf1, b1, h2, nullptr, nullptr,
        nullptr, nullptr, nullptr, nullptr, nullptr);
    sage_kernel< 64, 32, true ><<<1024, 256, 0, stream>>>(
        h2, idx, wf2, b2, nullptr, pool, gctr,
        lw0, lb0, lw1, lb1, out);
}

// Round 11
// 190.620 us; speedup vs baseline: 3.4909x; 1.2491x over previous
//
#include <hip/hip_runtime.h>

#define G 128
#define P 512
#define K 16
#define NPTS (G * P)   // 65536

typedef _Float16 half8 __attribute__((ext_vector_type(8)));
typedef float    floatx4 __attribute__((ext_vector_type(4)));

__device__ __forceinline__ unsigned uminu(unsigned a, unsigned b) { return a < b ? a : b; }

// compare-exchange: a=min, b=max (folds to v_min_u32 + v_max_u32)
__device__ __forceinline__ void ce(unsigned& a, unsigned& b) {
    const unsigned lo = a < b ? a : b;
    const unsigned hi = a < b ? b : a;
    a = lo; b = hi;
}

// Batcher odd-even mergesort, n=16 (63 CEs, fully unrolled)
__device__ __forceinline__ void sort16(unsigned k[16]) {
#pragma unroll
    for (int p = 1; p < 16; p <<= 1) {
#pragma unroll
        for (int q = p; q >= 1; q >>= 1) {
#pragma unroll
            for (int j = q % p; j + q < 16; j += 2 * q) {
#pragma unroll
                for (int i = 0; i < q; ++i) {
                    const int a = i + j, b2 = i + j + q;
                    if (b2 < 16 && (a / (2 * p)) == (b2 / (2 * p)))
                        ce(k[a], k[b2]);
                }
            }
        }
    }
}

// best (sorted asc) := sorted 16 smallest of best ∪ kb (kb sorted asc).
__device__ __forceinline__ void halfmerge(unsigned best[16], const unsigned kb[16]) {
#pragma unroll
    for (int i = 0; i < 16; ++i) best[i] = uminu(best[i], kb[15 - i]);
#pragma unroll
    for (int d = 8; d >= 1; d >>= 1)
#pragma unroll
        for (int i = 0; i < 16; ++i)
            if ((i & d) == 0) ce(best[i], best[i + d]);
}

// ---------------------------------------------------------------------------
// prep element: [wl;wr] fp32 -> fp16 MFMA B-fragment layout.
// frag (ntile,kt): lane l holds B[kt*32+(l>>4)*8+j][ntile*16+(l&15)], j=0..7.
// ---------------------------------------------------------------------------
template <int KT, int NIN, int NOUT>
__device__ __forceinline__ void prep_elem(int e, const float* __restrict__ wl,
                                          const float* __restrict__ wr,
                                          _Float16* __restrict__ wf) {
    const int fr   = e >> 9;
    const int lane = (e >> 3) & 63;
    const int j    = e & 7;
    const int ntile = fr / KT;
    const int kt    = fr - ntile * KT;
    const int k = kt * 32 + ((lane >> 4) << 3) + j;
    const int n = ntile * 16 + (lane & 15);
    const float v = (k < NIN) ? wl[k * NOUT + n] : wr[(k - NIN) * NOUT + n];
    wf[e] = (_Float16)v;
}

// ---------------------------------------------------------------------------
// Fused pre-pass: blocks [0,1024) = KNN, [1024,3072) = x fp32->fp16 cvt,
// [3072,3152) = weight prep. (proven in round 8)
// ---------------------------------------------------------------------------
__global__ __launch_bounds__(512, 4)
void pre_kernel(const int* __restrict__ coo, int* __restrict__ idx_out,
                const float* __restrict__ x, _Float16* __restrict__ x16,
                const float* __restrict__ wl0, const float* __restrict__ wr0,
                const float* __restrict__ wl1, const float* __restrict__ wr1,
                const float* __restrict__ wl2, const float* __restrict__ wr2,
                _Float16* __restrict__ wf0, _Float16* __restrict__ wf1,
                _Float16* __restrict__ wf2) {
    __shared__ float2 sxy[P];
    __shared__ unsigned mk[7][64][17];
    const int b   = blockIdx.x;
    const int tid = threadIdx.x;

    if (b < 1024) {
        // ---------------- KNN ----------------
        const int g   = b >> 3;
        const int t0  = (b & 7) * 64;
        const int tgt = tid & 63;
        const int sub = tid >> 6;          // 0..7, wave-uniform

        for (int i = tid; i < P; i += 512) {
            const int* cp = coo + (size_t)(g * P + i) * 3;
            sxy[i] = make_float2((float)cp[0], (float)cp[1]);
        }
        __syncthreads();

        const int tg = t0 + tgt;
        const float px = sxy[tg].x, py = sxy[tg].y;

        unsigned best[K];
#pragma unroll
        for (int k = 0; k < K; ++k) best[k] = 0xFFFFFFF0u + k;  // sorted tail

        const int s0 = sub * 64;
#pragma unroll
        for (int batch = 0; batch < 4; ++batch) {
            unsigned kb[K];
#pragma unroll
            for (int j = 0; j < 16; ++j) {
                const int s = s0 + batch * 16 + j;
                const float2 c = sxy[s];              // uniform -> broadcast
                const float dx = px - c.x, dy = py - c.y;
                const float keyf = fmaf(fmaf(dx, dx, dy * dy), 512.f, (float)s);
                unsigned key = (unsigned)keyf;        // exact (< 2^20)
                if (s == tg) key = 0xFFFFFFFFu;       // loop=False
                kb[j] = key;
            }
            sort16(kb);
            halfmerge(best, kb);
        }

        // single-barrier merge: subs 1-7 publish, sub 0 folds all 7
        if (sub != 0) {
#pragma unroll
            for (int k = 0; k < K; ++k) mk[sub - 1][tgt][k] = best[k];
        }
        __syncthreads();
        if (sub == 0) {
#pragma unroll 1
            for (int ss = 0; ss < 7; ++ss) {
                unsigned pb[K];
#pragma unroll
                for (int k = 0; k < K; ++k) pb[k] = mk[ss][tgt][k];
                halfmerge(best, pb);
            }
            int4* op = (int4*)(idx_out + (size_t)(g * P + tg) * K);
#pragma unroll
            for (int q4 = 0; q4 < 4; ++q4) {
                int4 o;
                o.x = (int)(best[q4 * 4 + 0] & (unsigned)(P - 1));
                o.y = (int)(best[q4 * 4 + 1] & (unsigned)(P - 1));
                o.z = (int)(best[q4 * 4 + 2] & (unsigned)(P - 1));
                o.w = (int)(best[q4 * 4 + 3] & (unsigned)(P - 1));
                op[q4] = o;
            }
        }
    } else if (b < 3072) {
        // ---------------- cvt: x fp32 -> fp16, 8 elems/thread ----------------
        const int i = (b - 1024) * 512 + tid;      // < 1,048,576 exactly
        const float4* p = (const float4*)(x + (size_t)i * 8);
        const float4 a = p[0], bq = p[1];
        half8 o;
        o[0] = (_Float16)a.x;  o[1] = (_Float16)a.y;
        o[2] = (_Float16)a.z;  o[3] = (_Float16)a.w;
        o[4] = (_Float16)bq.x; o[5] = (_Float16)bq.y;
        o[6] = (_Float16)bq.z; o[7] = (_Float16)bq.w;
        *(half8*)(x16 + (size_t)i * 8) = o;
    } else {
        // ---------------- prep ----------------
        const int e = (b - 3072) * 512 + tid;      // < 40,960 exactly
        if (e < 24576)      prep_elem<8, 128, 96>(e,         wl0, wr0, wf0);
        else if (e < 36864) prep_elem<6,  96, 64>(e - 24576, wl1, wr1, wf1);
        else                prep_elem<4,  64, 32>(e - 36864, wl2, wr2, wf2);
    }
}

// ---------------------------------------------------------------------------
// Fused SAGE (layers 0,1): out = relu([mean_nbr(h) | h] @ [wl;wr] + b).
// Proven round-8 structure: 256 thr / 4 waves, 64 points, XCD-swizzled
// (graph g -> XCD g%8), mean-half in LDS (stride 136), root A-frags global.
// ---------------------------------------------------------------------------
template <int CIN, int NOUT>
__global__ __launch_bounds__(256, 4)
void sage_kernel(const _Float16* __restrict__ hin, const int* __restrict__ idxg,
                 const _Float16* __restrict__ wf, const float* __restrict__ bias,
                 _Float16* __restrict__ hout) {
    constexpr int KTm = CIN / 32;     // mean-half MFMA k-steps
    constexpr int KT  = CIN / 16;     // total k-steps (mean + root)
    constexpr int NH  = NOUT / 32;    // N-tiles per wave
    constexpr int RS  = 136;          // LDS row stride in halves

    __shared__ _Float16 As[64 * RS];  // 17 KB

    const int tid  = threadIdx.x;
    const int b    = blockIdx.x;       // 0..1023
    const int slot = b >> 3;
    const int g    = (b & 7) | ((slot & 15) << 3);
    const int n0   = g * P + (slot >> 4) * 64;
    const _Float16* __restrict__ hg = hin + (size_t)(g * P) * CIN;

    const int pt = tid >> 2;
    const int q  = tid & 3;

    // 16 neighbor indices -> registers
    const int4* ip = (const int4*)(idxg + (size_t)(n0 + pt) * K);
    const int4 na = ip[0], nb4 = ip[1], nc = ip[2], nd = ip[3];
    const int nn[16] = {na.x, na.y, na.z, na.w, nb4.x, nb4.y, nb4.z, nb4.w,
                        nc.x, nc.y, nc.z, nc.w, nd.x, nd.y, nd.z, nd.w};

#pragma unroll 1
    for (int c = 0; c < KTm; ++c) {
        const int ch = c * 32 + q * 8;
        half8 a0 = {}; half8 a1 = {};
#pragma unroll
        for (int k = 0; k < 16; k += 4) {
            const half8 v0 = *(const half8*)(hg + (size_t)nn[k + 0] * CIN + ch);
            const half8 v1 = *(const half8*)(hg + (size_t)nn[k + 1] * CIN + ch);
            const half8 v2 = *(const half8*)(hg + (size_t)nn[k + 2] * CIN + ch);
            const half8 v3 = *(const half8*)(hg + (size_t)nn[k + 3] * CIN + ch);
            a0 += v0; a1 += v1; a0 += v2; a1 += v3;
        }
        half8 m;
#pragma unroll
        for (int e = 0; e < 8; ++e)
            m[e] = (_Float16)(((float)a0[e] + (float)a1[e]) * 0.0625f);
        *(half8*)&As[pt * RS + (c * 4 + q) * 8] = m;
    }

    const int l  = tid & 63;
    const int wv = tid >> 6;
    const int mh = wv & 1;
    const int nh = wv >> 1;
    const int lm = l & 15, lq = l >> 4;

    float bs[NH];
#pragma unroll
    for (int nt = 0; nt < NH; ++nt)
        bs[nt] = bias[nh * (NOUT / 2) + nt * 16 + lm];

    __syncthreads();

    floatx4 acc[2][NH];
#pragma unroll
    for (int mt = 0; mt < 2; ++mt)
#pragma unroll
        for (int nt = 0; nt < NH; ++nt) {
            floatx4 z = {0.f, 0.f, 0.f, 0.f};
            acc[mt][nt] = z;
        }

#pragma unroll
    for (int kt = 0; kt < KT; ++kt) {
        half8 bfr[NH];
#pragma unroll
        for (int nt = 0; nt < NH; ++nt) {
            const int ng = nh * NH + nt;
            bfr[nt] = *(const half8*)(wf + ((size_t)(ng * KT + kt) * 64 + l) * 8);
        }
#pragma unroll
        for (int mt = 0; mt < 2; ++mt) {
            const int row = mh * 32 + mt * 16 + lm;
            half8 a;
            if (kt < KTm) {
                a = *(const half8*)&As[row * RS + (kt * 4 + lq) * 8];
            } else {
                a = *(const half8*)(hin + (size_t)(n0 + row) * CIN +
                                    (kt - KTm) * 32 + lq * 8);
            }
#pragma unroll
            for (int nt = 0; nt < NH; ++nt)
                acc[mt][nt] = __builtin_amdgcn_mfma_f32_16x16x32_f16(
                    a, bfr[nt], acc[mt][nt], 0, 0, 0);
        }
    }

#pragma unroll
    for (int mt = 0; mt < 2; ++mt)
#pragma unroll
        for (int nt = 0; nt < NH; ++nt) {
            const int n = nh * (NOUT / 2) + nt * 16 + lm;
#pragma unroll
            for (int r = 0; r < 4; ++r) {
                const int p = n0 + mh * 32 + mt * 16 + lq * 4 + r;
                float v = acc[mt][nt][r] + bs[nt];
                v = v > 0.f ? v : 0.f;
                hout[(size_t)p * NOUT + n] = (_Float16)v;
            }
        }
}

// ---------------------------------------------------------------------------
// Fused SAGE L2 + max-pool + MLP head: ONE block per graph (128 blocks,
// 256 thr / 4 waves). No cross-block sync (round-9/10 lesson: any agent-scope
// fence/atomic per block costs ~µs on multi-XCD gfx950).
// Wave w handles points [128w,128w+128) = 8 M-tiles; A-frags gathered
// directly from L2-hot h2 (graph g on XCD g%8 matches producer); all 8
// B-frags (2 N-tiles x 4 kt) live in registers; C never leaves registers:
// bias+relu+running-max -> shfl/LDS pool -> 32x32 head -> out[g*3..].
// ---------------------------------------------------------------------------
__global__ __launch_bounds__(256)
void sage2_head_kernel(const _Float16* __restrict__ h2,
                       const int* __restrict__ idxg,
                       const _Float16* __restrict__ wf2,
                       const float* __restrict__ b2,
                       const float* __restrict__ lw0, const float* __restrict__ lb0,
                       const float* __restrict__ lw1, const float* __restrict__ lb1,
                       float* __restrict__ out) {
    constexpr int CIN = 64;
    __shared__ float ps[4][32];
    __shared__ float pooled[32];
    __shared__ float hid[32];

    const int g   = blockIdx.x;              // graph; XCD g%8
    const int tid = threadIdx.x;
    const int l   = tid & 63;
    const int wv  = tid >> 6;
    const int lm  = l & 15, lq = l >> 4;

    const _Float16* __restrict__ hg = h2 + (size_t)(g * P) * CIN;
    const int* __restrict__ ig = idxg + (size_t)(g * P) * K;

    // B fragments (nt in {0,1}, kt in 0..3) + bias, in registers
    half8 bf[2][4];
#pragma unroll
    for (int nt = 0; nt < 2; ++nt)
#pragma unroll
        for (int kt = 0; kt < 4; ++kt)
            bf[nt][kt] = *(const half8*)(wf2 + ((size_t)((nt * 4 + kt) * 64 + l)) * 8);
    const float bs0 = b2[lm], bs1 = b2[16 + lm];

    float pmax0 = 0.f, pmax1 = 0.f;   // relu output >= 0, so 0 is a safe floor

#pragma unroll 1
    for (int mt = 0; mt < 8; ++mt) {
        const int p = wv * 128 + mt * 16 + lm;     // A-row point (local)
        // neighbor list for point p
        const int4* ip = (const int4*)(ig + (size_t)p * K);
        const int4 na = ip[0], nb4 = ip[1], nc = ip[2], nd = ip[3];
        const int nn[16] = {na.x, na.y, na.z, na.w, nb4.x, nb4.y, nb4.z, nb4.w,
                            nc.x, nc.y, nc.z, nc.w, nd.x, nd.y, nd.z, nd.w};

        floatx4 acc0 = {0.f, 0.f, 0.f, 0.f};
        floatx4 acc1 = {0.f, 0.f, 0.f, 0.f};

        // mean part: kt 0,1 (concat-K 0..63)
#pragma unroll
        for (int kt = 0; kt < 2; ++kt) {
            const int off = kt * 32 + lq * 8;
            half8 a0 = {}; half8 a1 = {};
#pragma unroll
            for (int k = 0; k < 8; ++k)
                a0 += *(const half8*)(hg + (size_t)nn[k] * CIN + off);
#pragma unroll
            for (int k = 8; k < 16; ++k)
                a1 += *(const half8*)(hg + (size_t)nn[k] * CIN + off);
            half8 am;
#pragma unroll
            for (int e = 0; e < 8; ++e)
                am[e] = (_Float16)(((float)a0[e] + (float)a1[e]) * 0.0625f);
            acc0 = __builtin_amdgcn_mfma_f32_16x16x32_f16(am, bf[0][kt], acc0, 0, 0, 0);
            acc1 = __builtin_amdgcn_mfma_f32_16x16x32_f16(am, bf[1][kt], acc1, 0, 0, 0);
        }
        // root part: kt 2,3 (concat-K 64..127)
#pragma unroll
        for (int kt = 2; kt < 4; ++kt) {
            const int off = (kt - 2) * 32 + lq * 8;
            const half8 ar = *(const half8*)(hg + (size_t)p * CIN + off);
            acc0 = __builtin_amdgcn_mfma_f32_16x16x32_f16(ar, bf[0][kt], acc0, 0, 0, 0);
            acc1 = __builtin_amdgcn_mfma_f32_16x16x32_f16(ar, bf[1][kt], acc1, 0, 0, 0);
        }
        // bias + relu + running max (C: col=lm, rows=lq*4+r -> all covered)
#pragma unroll
        for (int r = 0; r < 4; ++r) {
            const float v0 = acc0[r] + bs0;
            const float v1 = acc1[r] + bs1;
            pmax0 = fmaxf(pmax0, v0);    // relu folded: pmax starts at 0
            pmax1 = fmaxf(pmax1, v1);
        }
    }

    // reduce over lq (lanes 16 apart share channel lm)
    pmax0 = fmaxf(pmax0, __shfl_xor(pmax0, 16, 64));
    pmax0 = fmaxf(pmax0, __shfl_xor(pmax0, 32, 64));
    pmax1 = fmaxf(pmax1, __shfl_xor(pmax1, 16, 64));
    pmax1 = fmaxf(pmax1, __shfl_xor(pmax1, 32, 64));
    if (lq == 0) { ps[wv][lm] = pmax0; ps[wv][16 + lm] = pmax1; }
    __syncthreads();

    if (tid < 32) {
        const float m = fmaxf(fmaxf(ps[0][tid], ps[1][tid]),
                              fmaxf(ps[2][tid], ps[3][tid]));
        pooled[tid] = m;
    }
    __syncthreads();
    if (tid < 32) {
        float a = lb0[tid];
#pragma unroll
        for (int i = 0; i < 32; ++i) a += pooled[i] * lw0[i * 32 + tid];
        hid[tid] = a > 0.f ? a : 0.f;
    }
    __syncthreads();
    if (tid < 3) {
        float a = lb1[tid];
#pragma unroll
        for (int i = 0; i < 32; ++i) a += hid[i] * lw1[i * 3 + tid];
        out[g * 3 + tid] = a;
    }
}

// ---------------------------------------------------------------------------
extern "C" void kernel_launch(void* const* d_in, const int* in_sizes, int n_in,
                              void* d_out, int out_size, void* d_ws, size_t ws_size,
                              hipStream_t stream) {
    const float* x   = (const float*)d_in[0];
    const int*   coo = (const int*)  d_in[1];
    const float* wl0 = (const float*)d_in[2];
    const float* wr0 = (const float*)d_in[3];
    const float* b0  = (const float*)d_in[4];
    const float* wl1 = (const float*)d_in[5];
    const float* wr1 = (const float*)d_in[6];
    const float* b1  = (const float*)d_in[7];
    const float* wl2 = (const float*)d_in[8];
    const float* wr2 = (const float*)d_in[9];
    const float* b2  = (const float*)d_in[10];
    const float* lw0 = (const float*)d_in[11];
    const float* lb0 = (const float*)d_in[12];
    const float* lw1 = (const float*)d_in[13];
    const float* lb1 = (const float*)d_in[14];
    float* out = (float*)d_out;

    char* ws = (char*)d_ws;
    // Workspace (bytes):
    //   wf0 : 49,152      @ 0
    //   wf1 : 24,576      @ 49,152
    //   wf2 :  8,192      @ 73,728
    //   idx :  4,194,304  @ 81,920
    //   x16 : 16,777,216  @ 4,276,224   (65536 x 128 fp16)
    //   h1  : 12,582,912  @ 21,053,440  (fp16)
    //   h2  :  8,388,608  @ 33,636,352  (fp16)  end ~42 MB
    _Float16* wf0 = (_Float16*)(ws + 0);
    _Float16* wf1 = (_Float16*)(ws + 49152);
    _Float16* wf2 = (_Float16*)(ws + 73728);
    int*      idx = (int*)     (ws + 81920);
    _Float16* x16 = (_Float16*)(ws + 4276224);
    _Float16* h1  = (_Float16*)(ws + 21053440);
    _Float16* h2  = (_Float16*)(ws + 33636352);

    pre_kernel<<<3152, 512, 0, stream>>>(coo, idx, x, x16,
                                         wl0, wr0, wl1, wr1, wl2, wr2,
                                         wf0, wf1, wf2);

    sage_kernel<128, 96><<<1024, 256, 0, stream>>>(x16, idx, wf0, b0, h1);
    sage_kernel< 96, 64><<<1024, 256, 0, stream>>>(h1,  idx, wf1, b1, h2);

    sage2_head_kernel<<<G, 256, 0, stream>>>(h2, idx, wf2, b2,
                                             lw0, lb0, lw1, lb1, out);
}

// Round 12
// 162.138 us; speedup vs baseline: 4.1041x; 1.1757x over previous
//
#include <hip/hip_runtime.h>

#define G 128
#define P 512
#define K 16
#define NPTS (G * P)   // 65536

typedef _Float16 half8 __attribute__((ext_vector_type(8)));
typedef float    floatx4 __attribute__((ext_vector_type(4)));

__device__ __forceinline__ unsigned uminu(unsigned a, unsigned b) { return a < b ? a : b; }

// compare-exchange: a=min, b=max (folds to v_min_u32 + v_max_u32)
__device__ __forceinline__ void ce(unsigned& a, unsigned& b) {
    const unsigned lo = a < b ? a : b;
    const unsigned hi = a < b ? b : a;
    a = lo; b = hi;
}

// Batcher odd-even mergesort, n=16 (63 CEs, fully unrolled)
__device__ __forceinline__ void sort16(unsigned k[16]) {
#pragma unroll
    for (int p = 1; p < 16; p <<= 1) {
#pragma unroll
        for (int q = p; q >= 1; q >>= 1) {
#pragma unroll
            for (int j = q % p; j + q < 16; j += 2 * q) {
#pragma unroll
                for (int i = 0; i < q; ++i) {
                    const int a = i + j, b2 = i + j + q;
                    if (b2 < 16 && (a / (2 * p)) == (b2 / (2 * p)))
                        ce(k[a], k[b2]);
                }
            }
        }
    }
}

// best (sorted asc) := sorted 16 smallest of best ∪ kb (kb sorted asc).
__device__ __forceinline__ void halfmerge(unsigned best[16], const unsigned kb[16]) {
#pragma unroll
    for (int i = 0; i < 16; ++i) best[i] = uminu(best[i], kb[15 - i]);
#pragma unroll
    for (int d = 8; d >= 1; d >>= 1)
#pragma unroll
        for (int i = 0; i < 16; ++i)
            if ((i & d) == 0) ce(best[i], best[i + d]);
}

// ---------------------------------------------------------------------------
// prep element: [wl;wr] fp32 -> fp16 MFMA B-fragment layout.
// frag (ntile,kt): lane l holds B[kt*32+(l>>4)*8+j][ntile*16+(l&15)], j=0..7.
// ---------------------------------------------------------------------------
template <int KT, int NIN, int NOUT>
__device__ __forceinline__ void prep_elem(int e, const float* __restrict__ wl,
                                          const float* __restrict__ wr,
                                          _Float16* __restrict__ wf) {
    const int fr   = e >> 9;
    const int lane = (e >> 3) & 63;
    const int j    = e & 7;
    const int ntile = fr / KT;
    const int kt    = fr - ntile * KT;
    const int k = kt * 32 + ((lane >> 4) << 3) + j;
    const int n = ntile * 16 + (lane & 15);
    const float v = (k < NIN) ? wl[k * NOUT + n] : wr[(k - NIN) * NOUT + n];
    wf[e] = (_Float16)v;
}

// ---------------------------------------------------------------------------
// Fused pre-pass: blocks [0,1024) = KNN, [1024,3072) = x fp32->fp16 cvt,
// [3072,3152) = weight prep. (proven in round 8)
// ---------------------------------------------------------------------------
__global__ __launch_bounds__(512, 4)
void pre_kernel(const int* __restrict__ coo, int* __restrict__ idx_out,
                const float* __restrict__ x, _Float16* __restrict__ x16,
                const float* __restrict__ wl0, const float* __restrict__ wr0,
                const float* __restrict__ wl1, const float* __restrict__ wr1,
                const float* __restrict__ wl2, const float* __restrict__ wr2,
                _Float16* __restrict__ wf0, _Float16* __restrict__ wf1,
                _Float16* __restrict__ wf2) {
    __shared__ float2 sxy[P];
    __shared__ unsigned mk[7][64][17];
    const int b   = blockIdx.x;
    const int tid = threadIdx.x;

    if (b < 1024) {
        // ---------------- KNN ----------------
        const int g   = b >> 3;
        const int t0  = (b & 7) * 64;
        const int tgt = tid & 63;
        const int sub = tid >> 6;          // 0..7, wave-uniform

        for (int i = tid; i < P; i += 512) {
            const int* cp = coo + (size_t)(g * P + i) * 3;
            sxy[i] = make_float2((float)cp[0], (float)cp[1]);
        }
        __syncthreads();

        const int tg = t0 + tgt;
        const float px = sxy[tg].x, py = sxy[tg].y;

        unsigned best[K];
#pragma unroll
        for (int k = 0; k < K; ++k) best[k] = 0xFFFFFFF0u + k;  // sorted tail

        const int s0 = sub * 64;
#pragma unroll
        for (int batch = 0; batch < 4; ++batch) {
            unsigned kb[K];
#pragma unroll
            for (int j = 0; j < 16; ++j) {
                const int s = s0 + batch * 16 + j;
                const float2 c = sxy[s];              // uniform -> broadcast
                const float dx = px - c.x, dy = py - c.y;
                const float keyf = fmaf(fmaf(dx, dx, dy * dy), 512.f, (float)s);
                unsigned key = (unsigned)keyf;        // exact (< 2^20)
                if (s == tg) key = 0xFFFFFFFFu;       // loop=False
                kb[j] = key;
            }
            sort16(kb);
            halfmerge(best, kb);
        }

        // single-barrier merge: subs 1-7 publish, sub 0 folds all 7
        if (sub != 0) {
#pragma unroll
            for (int k = 0; k < K; ++k) mk[sub - 1][tgt][k] = best[k];
        }
        __syncthreads();
        if (sub == 0) {
#pragma unroll 1
            for (int ss = 0; ss < 7; ++ss) {
                unsigned pb[K];
#pragma unroll
                for (int k = 0; k < K; ++k) pb[k] = mk[ss][tgt][k];
                halfmerge(best, pb);
            }
            int4* op = (int4*)(idx_out + (size_t)(g * P + tg) * K);
#pragma unroll
            for (int q4 = 0; q4 < 4; ++q4) {
                int4 o;
                o.x = (int)(best[q4 * 4 + 0] & (unsigned)(P - 1));
                o.y = (int)(best[q4 * 4 + 1] & (unsigned)(P - 1));
                o.z = (int)(best[q4 * 4 + 2] & (unsigned)(P - 1));
                o.w = (int)(best[q4 * 4 + 3] & (unsigned)(P - 1));
                op[q4] = o;
            }
        }
    } else if (b < 3072) {
        // ---------------- cvt: x fp32 -> fp16, 8 elems/thread ----------------
        const int i = (b - 1024) * 512 + tid;      // < 1,048,576 exactly
        const float4* p = (const float4*)(x + (size_t)i * 8);
        const float4 a = p[0], bq = p[1];
        half8 o;
        o[0] = (_Float16)a.x;  o[1] = (_Float16)a.y;
        o[2] = (_Float16)a.z;  o[3] = (_Float16)a.w;
        o[4] = (_Float16)bq.x; o[5] = (_Float16)bq.y;
        o[6] = (_Float16)bq.z; o[7] = (_Float16)bq.w;
        *(half8*)(x16 + (size_t)i * 8) = o;
    } else {
        // ---------------- prep ----------------
        const int e = (b - 3072) * 512 + tid;      // < 40,960 exactly
        if (e < 24576)      prep_elem<8, 128, 96>(e,         wl0, wr0, wf0);
        else if (e < 36864) prep_elem<6,  96, 64>(e - 24576, wl1, wr1, wf1);
        else                prep_elem<4,  64, 32>(e - 36864, wl2, wr2, wf2);
    }
}

// ---------------------------------------------------------------------------
// Fused SAGE: out = relu([mean_nbr(h) | h] @ [wl;wr] + b), f16 MFMA.
// Proven round-8 structure: 1024 blocks, 256 thr / 4 waves, 64 points,
// XCD-swizzled (graph g -> XCD g%8), mean-half in LDS (stride 136),
// root A-frags from global.
// POOL=true (L2): NO h3 store, NO cross-block sync — pure intra-block
// relu+channel-max epilogue -> pool_part[g*8+chunk][32]. (R10/R11 lessons:
// agent-scope fences cost ~µs/block; <1024 blocks starves the chip.)
// ---------------------------------------------------------------------------
template <int CIN, int NOUT, bool POOL>
__global__ __launch_bounds__(256, 4)
void sage_kernel(const _Float16* __restrict__ hin, const int* __restrict__ idxg,
                 const _Float16* __restrict__ wf, const float* __restrict__ bias,
                 _Float16* __restrict__ hout, float* __restrict__ pool_part) {
    constexpr int KTm = CIN / 32;     // mean-half MFMA k-steps
    constexpr int KT  = CIN / 16;     // total k-steps (mean + root)
    constexpr int NH  = NOUT / 32;    // N-tiles per wave
    constexpr int RS  = 136;          // LDS row stride in halves

    __shared__ _Float16 As[64 * RS];  // 17 KB

    const int tid  = threadIdx.x;
    const int b    = blockIdx.x;       // 0..1023
    const int slot = b >> 3;
    const int g    = (b & 7) | ((slot & 15) << 3);
    const int chunk = slot >> 4;
    const int n0   = g * P + chunk * 64;
    const _Float16* __restrict__ hg = hin + (size_t)(g * P) * CIN;

    const int pt = tid >> 2;
    const int q  = tid & 3;

    // 16 neighbor indices -> registers
    const int4* ip = (const int4*)(idxg + (size_t)(n0 + pt) * K);
    const int4 na = ip[0], nb4 = ip[1], nc = ip[2], nd = ip[3];
    const int nn[16] = {na.x, na.y, na.z, na.w, nb4.x, nb4.y, nb4.z, nb4.w,
                        nc.x, nc.y, nc.z, nc.w, nd.x, nd.y, nd.z, nd.w};

#pragma unroll 1
    for (int c = 0; c < KTm; ++c) {
        const int ch = c * 32 + q * 8;
        half8 a0 = {}; half8 a1 = {};
#pragma unroll
        for (int k = 0; k < 16; k += 4) {
            const half8 v0 = *(const half8*)(hg + (size_t)nn[k + 0] * CIN + ch);
            const half8 v1 = *(const half8*)(hg + (size_t)nn[k + 1] * CIN + ch);
            const half8 v2 = *(const half8*)(hg + (size_t)nn[k + 2] * CIN + ch);
            const half8 v3 = *(const half8*)(hg + (size_t)nn[k + 3] * CIN + ch);
            a0 += v0; a1 += v1; a0 += v2; a1 += v3;
        }
        half8 m;
#pragma unroll
        for (int e = 0; e < 8; ++e)
            m[e] = (_Float16)(((float)a0[e] + (float)a1[e]) * 0.0625f);
        *(half8*)&As[pt * RS + (c * 4 + q) * 8] = m;
    }

    const int l  = tid & 63;
    const int wv = tid >> 6;
    const int mh = wv & 1;
    const int nh = wv >> 1;
    const int lm = l & 15, lq = l >> 4;

    float bs[NH];
#pragma unroll
    for (int nt = 0; nt < NH; ++nt)
        bs[nt] = bias[nh * (NOUT / 2) + nt * 16 + lm];

    __syncthreads();

    floatx4 acc[2][NH];
#pragma unroll
    for (int mt = 0; mt < 2; ++mt)
#pragma unroll
        for (int nt = 0; nt < NH; ++nt) {
            floatx4 z = {0.f, 0.f, 0.f, 0.f};
            acc[mt][nt] = z;
        }

#pragma unroll
    for (int kt = 0; kt < KT; ++kt) {
        half8 bfr[NH];
#pragma unroll
        for (int nt = 0; nt < NH; ++nt) {
            const int ng = nh * NH + nt;
            bfr[nt] = *(const half8*)(wf + ((size_t)(ng * KT + kt) * 64 + l) * 8);
        }
#pragma unroll
        for (int mt = 0; mt < 2; ++mt) {
            const int row = mh * 32 + mt * 16 + lm;
            half8 a;
            if (kt < KTm) {
                a = *(const half8*)&As[row * RS + (kt * 4 + lq) * 8];
            } else {
                a = *(const half8*)(hin + (size_t)(n0 + row) * CIN +
                                    (kt - KTm) * 32 + lq * 8);
            }
#pragma unroll
            for (int nt = 0; nt < NH; ++nt)
                acc[mt][nt] = __builtin_amdgcn_mfma_f32_16x16x32_f16(
                    a, bfr[nt], acc[mt][nt], 0, 0, 0);
        }
    }

    if constexpr (!POOL) {
#pragma unroll
        for (int mt = 0; mt < 2; ++mt)
#pragma unroll
            for (int nt = 0; nt < NH; ++nt) {
                const int n = nh * (NOUT / 2) + nt * 16 + lm;
#pragma unroll
                for (int r = 0; r < 4; ++r) {
                    const int p = n0 + mh * 32 + mt * 16 + lq * 4 + r;
                    float v = acc[mt][nt][r] + bs[nt];
                    v = v > 0.f ? v : 0.f;
                    hout[(size_t)p * NOUT + n] = (_Float16)v;
                }
            }
    } else {
        // ---- intra-block relu+max epilogue (NH==1): channel = nh*16+lm ----
        __shared__ float ps[4][16];
        float vmax = 0.f;                 // relu floor
#pragma unroll
        for (int mt = 0; mt < 2; ++mt)
#pragma unroll
            for (int r = 0; r < 4; ++r)
                vmax = fmaxf(vmax, acc[mt][0][r] + bs[0]);
        vmax = fmaxf(vmax, __shfl_xor(vmax, 16, 64));
        vmax = fmaxf(vmax, __shfl_xor(vmax, 32, 64));
        if (lq == 0) ps[wv][lm] = vmax;
        __syncthreads();
        if (tid < 32) {
            const int nh2 = tid >> 4, lm2 = tid & 15;
            pool_part[(size_t)(g * 8 + chunk) * 32 + tid] =
                fmaxf(ps[nh2 * 2][lm2], ps[nh2 * 2 + 1][lm2]);
        }
    }
}

// ---------------------------------------------------------------------------
// Head: reduce pool_part (8 partials/graph) -> 32x32 MLP -> 32x3.
// 128 blocks x 64 thr; reads 16 KB total.
// ---------------------------------------------------------------------------
__global__ __launch_bounds__(64)
void head_kernel(const float* __restrict__ pool_part,
                 const float* __restrict__ lw0, const float* __restrict__ lb0,
                 const float* __restrict__ lw1, const float* __restrict__ lb1,
                 float* __restrict__ out) {
    __shared__ float pooled[32];
    __shared__ float hid[32];
    const int g = blockIdx.x;
    const int t = threadIdx.x;

    if (t < 32) {
        float m = pool_part[(size_t)(g * 8) * 32 + t];
#pragma unroll
        for (int c = 1; c < 8; ++c)
            m = fmaxf(m, pool_part[(size_t)(g * 8 + c) * 32 + t]);
        pooled[t] = m;
    }
    __syncthreads();
    if (t < 32) {
        float a = lb0[t];
#pragma unroll
        for (int i = 0; i < 32; ++i) a += pooled[i] * lw0[i * 32 + t];
        hid[t] = a > 0.f ? a : 0.f;
    }
    __syncthreads();
    if (t < 3) {
        float a = lb1[t];
#pragma unroll
        for (int i = 0; i < 32; ++i) a += hid[i] * lw1[i * 3 + t];
        out[g * 3 + t] = a;
    }
}

// ---------------------------------------------------------------------------
extern "C" void kernel_launch(void* const* d_in, const int* in_sizes, int n_in,
                              void* d_out, int out_size, void* d_ws, size_t ws_size,
                              hipStream_t stream) {
    const float* x   = (const float*)d_in[0];
    const int*   coo = (const int*)  d_in[1];
    const float* wl0 = (const float*)d_in[2];
    const float* wr0 = (const float*)d_in[3];
    const float* b0  = (const float*)d_in[4];
    const float* wl1 = (const float*)d_in[5];
    const float* wr1 = (const float*)d_in[6];
    const float* b1  = (const float*)d_in[7];
    const float* wl2 = (const float*)d_in[8];
    const float* wr2 = (const float*)d_in[9];
    const float* b2  = (const float*)d_in[10];
    const float* lw0 = (const float*)d_in[11];
    const float* lb0 = (const float*)d_in[12];
    const float* lw1 = (const float*)d_in[13];
    const float* lb1 = (const float*)d_in[14];
    float* out = (float*)d_out;

    char* ws = (char*)d_ws;
    // Workspace (bytes):
    //   wf0 : 49,152      @ 0
    //   wf1 : 24,576      @ 49,152
    //   wf2 :  8,192      @ 73,728
    //   idx :  4,194,304  @ 81,920
    //   x16 : 16,777,216  @ 4,276,224   (65536 x 128 fp16)
    //   h1  : 12,582,912  @ 21,053,440  (fp16)
    //   h2  :  8,388,608  @ 33,636,352  (fp16)
    //   pool:    131,072  @ 42,024,960  (1024 x 32 fp32)
    _Float16* wf0 = (_Float16*)(ws + 0);
    _Float16* wf1 = (_Float16*)(ws + 49152);
    _Float16* wf2 = (_Float16*)(ws + 73728);
    int*      idx = (int*)     (ws + 81920);
    _Float16* x16 = (_Float16*)(ws + 4276224);
    _Float16* h1  = (_Float16*)(ws + 21053440);
    _Float16* h2  = (_Float16*)(ws + 33636352);
    float*    pool= (float*)   (ws + 42024960);

    pre_kernel<<<3152, 512, 0, stream>>>(coo, idx, x, x16,
                                         wl0, wr0, wl1, wr1, wl2, wr2,
                                         wf0, wf1, wf2);

    sage_kernel<128, 96, false><<<1024, 256, 0, stream>>>(x16, idx, wf0, b0, h1, nullptr);
    sage_kernel< 96, 64, false><<<1024, 256, 0, stream>>>(h1,  idx, wf1, b1, h2, nullptr);
    sage_kernel< 64, 32, true ><<<1024, 256, 0, stream>>>(h2,  idx, wf2, b2, nullptr, pool);

    head_kernel<<<G, 64, 0, stream>>>(pool, lw0, lb0, lw1, lb1, out);
}